// Round 3
// baseline (582.412 us; speedup 1.0000x reference)
//
#include <hip/hip_runtime.h>

#define NS 128                 // samples per ray
#define SPL 8                  // samples per lane
#define NEAR_P 2.0f
#define FAR_P  6.0f

// 16 lanes per ray, 8 samples per lane, 4 rays per wave, 16 rays per block.
// Cross-lane traffic: 4-step scan + 1 shift + 16-op reduce = 21 DS ops per
// wave covering 4 rays (vs 31/ray in the 64-lane-per-ray version).
__global__ __launch_bounds__(256) void volrender_kernel(
    const float* __restrict__ sigmas,      // [nrays, 128]
    const float* __restrict__ radiances,   // [nrays, 128, 3]
    float* __restrict__ out_rgb,           // [nrays, 3]
    float* __restrict__ out_depth,         // [nrays]
    int nrays)
{
    const int tid  = threadIdx.x;
    const int lane = tid & 63;
    const int wave = tid >> 6;
    const int sub  = lane >> 4;            // ray within wave (0..3)
    const int sl   = lane & 15;            // lane within ray segment (0..15)

    const int ray = blockIdx.x * 16 + wave * 4 + sub;

    const float dz = (FAR_P - NEAR_P) / (float)(NS - 1);

    const float* sig = sigmas    + (size_t)ray * NS + sl * SPL;
    const float* rad = radiances + (size_t)ray * NS * 3 + sl * SPL * 3;

    // ---- issue all global loads up front (8x float4 per lane) ----
    const float4 s0 = *(const float4*)(sig);
    const float4 s1 = *(const float4*)(sig + 4);
    const float4 r0 = *(const float4*)(rad);
    const float4 r1 = *(const float4*)(rad + 4);
    const float4 r2 = *(const float4*)(rad + 8);
    const float4 r3 = *(const float4*)(rad + 12);
    const float4 r4 = *(const float4*)(rad + 16);
    const float4 r5 = *(const float4*)(rad + 20);

    const float sv[SPL] = {s0.x, s0.y, s0.z, s0.w, s1.x, s1.y, s1.z, s1.w};
    const float rv[SPL * 3] = {r0.x, r0.y, r0.z, r0.w,
                               r1.x, r1.y, r1.z, r1.w,
                               r2.x, r2.y, r2.z, r2.w,
                               r3.x, r3.y, r3.z, r3.w,
                               r4.x, r4.y, r4.z, r4.w,
                               r5.x, r5.y, r5.z, r5.w};

    // ---- local alpha / step-factor / inclusive cumprod (VALU only) ----
    float a[SPL], c[SPL];
    float run = 1.0f;
    #pragma unroll
    for (int j = 0; j < SPL; ++j) {
        const float d = (sl == 15 && j == SPL - 1) ? 1e10f : dz;  // z==127
        const float ej = __expf(-sv[j] * d);
        a[j] = 1.0f - ej;
        run *= (ej + 1e-10f);      // t_j = 1 - alpha + 1e-10
        c[j] = run;                // lane-local inclusive product
    }

    // ---- exclusive prefix product across the 16-lane segment ----
    float incl = run;
    #pragma unroll
    for (int off = 1; off < 16; off <<= 1) {
        const float v = __shfl_up(incl, off, 16);
        if (sl >= off) incl *= v;
    }
    float excl = __shfl_up(incl, 1, 16);
    if (sl == 0) excl = 1.0f;

    // ---- weights + weighted sums (VALU only) ----
    float pr = 0.f, pg = 0.f, pb = 0.f, pd = 0.f;
    const float zbase = NEAR_P + (float)(sl * SPL) * dz;
    #pragma unroll
    for (int j = 0; j < SPL; ++j) {
        const float w = a[j] * (excl * c[j]);
        pr += w * rv[3 * j];
        pg += w * rv[3 * j + 1];
        pb += w * rv[3 * j + 2];
        pd += w * (zbase + (float)j * dz);
    }

    // ---- segment tree-reduction (16 lanes) ----
    #pragma unroll
    for (int off = 8; off > 0; off >>= 1) {
        pr += __shfl_down(pr, off, 16);
        pg += __shfl_down(pg, off, 16);
        pb += __shfl_down(pb, off, 16);
        pd += __shfl_down(pd, off, 16);
    }

    if (sl == 0 && ray < nrays) {
        float* o = out_rgb + (size_t)ray * 3;
        o[0] = pr;
        o[1] = pg;
        o[2] = pb;
        out_depth[ray] = pd;
    }
}

extern "C" void kernel_launch(void* const* d_in, const int* in_sizes, int n_in,
                              void* d_out, int out_size, void* d_ws, size_t ws_size,
                              hipStream_t stream) {
    const float* sigmas    = (const float*)d_in[0];
    const float* radiances = (const float*)d_in[1];
    float* out = (float*)d_out;

    const int nrays = in_sizes[0] / NS;        // B * NUM_RAYS = 262144
    float* out_rgb   = out;                    // [nrays, 3]
    float* out_depth = out + (size_t)nrays * 3;

    const int raysPerBlock = 16;               // 4 waves x 4 rays/wave
    const int grid = (nrays + raysPerBlock - 1) / raysPerBlock;
    volrender_kernel<<<grid, 256, 0, stream>>>(sigmas, radiances, out_rgb, out_depth, nrays);
}